// Round 6
// baseline (340.574 us; speedup 1.0000x reference)
//
#include <hip/hip_runtime.h>

typedef _Float16 f16;
typedef _Float16 f16x8 __attribute__((ext_vector_type(8)));
typedef float f32x4 __attribute__((ext_vector_type(4)));

#define N_BOX 1805
#define NPIX 361
#define NCLS 20
#define MCAP 320          // LDS-mask capacity per class (actual n/class ~90)
#define GNW 29            // max mask words (ceil(1805/64))

__device__ __forceinline__ float leakyf(float x){ return x > 0.f ? x : 0.1f*x; }
__device__ __forceinline__ float sigmoidf_(float x){ return 1.f/(1.f + expf(-x)); }

// ---------------- small transpose: dst[C][R] = src[R][C] (fp32, for wrT/wpT) ----------------
__global__ void transpose_k(const float* __restrict__ src, float* __restrict__ dst, int R, int C){
  int i = blockIdx.x*256 + threadIdx.x;
  if (i < R*C){ int r = i / C, c = i % C; dst[c*R + r] = src[i]; }
}

// ---------------- weight prep: w[Cout][Cin][9] fp32 -> whi/wlo[Cout][9][Cin] f16, scaled x64 ----------------
__global__ void wprep_k(const float* __restrict__ w, f16* __restrict__ whi, f16* __restrict__ wlo,
                        int Cin, int total){
  int i = blockIdx.x*256 + threadIdx.x;   // over Cout*Cin
  if (i >= total) return;
  int co = i / Cin, ci = i - co*Cin;
  const float* src = w + (size_t)i*9;     // [co][ci][0..9)
  int K9 = 9*Cin;
  size_t dbase = (size_t)co*K9 + ci;
  #pragma unroll
  for (int t = 0; t < 9; ++t){
    float v = src[t]*64.f;
    f16 hi = (f16)v;
    f16 lo = (f16)(v - (float)hi);
    whi[dbase + (size_t)t*Cin] = hi;
    wlo[dbase + (size_t)t*Cin] = lo;
  }
}

// ---------------- act1 prep: feat3[1024][361] fp32 -> a1hi/a1lo[361][1024] f16 ----------------
__global__ void act1prep_k(const float* __restrict__ feat3, f16* __restrict__ ah, f16* __restrict__ al){
  int i = blockIdx.x*256 + threadIdx.x;  // over 361*1024
  if (i >= NPIX*1024) return;
  int p = i >> 10, c = i & 1023;
  float v = feat3[c*NPIX + p];
  f16 hi = (f16)v; f16 lo = (f16)(v - (float)hi);
  ah[i] = hi; al[i] = lo;
}

// ---------------- reorg path: leaky(conv1x1(feat2, wr)+br) -> reorg -> cat[ ][0:256) f16 hi/lo ----------------
__global__ __launch_bounds__(256) void reorg_conv_k(const float* __restrict__ feat2,
    const float* __restrict__ wrT, const float* __restrict__ br,
    f16* __restrict__ cath, f16* __restrict__ catl){
  int c  = threadIdx.x & 63;
  int pq = threadIdx.x >> 6;
  int pix = blockIdx.x*4 + pq;      // 0..1443
  int y = pix / 38, x = pix % 38;
  __shared__ float s_in[64][4];
  float acc = br[c];
  for (int cb = 0; cb < 512; cb += 64){
    __syncthreads();
    { int k = threadIdx.x >> 2, pp = threadIdx.x & 3;
      s_in[k][pp] = feat2[(cb + k)*1444 + blockIdx.x*4 + pp]; }
    __syncthreads();
    #pragma unroll
    for (int k = 0; k < 64; ++k)
      acc = fmaf(wrT[(cb+k)*64 + c], s_in[k][pq], acc);
  }
  float v = leakyf(acc);
  int co = ((y & 1)*2 + (x & 1))*64 + c;   // reorg channel mapping
  int p = (y>>1)*19 + (x>>1);
  f16 hi = (f16)v; f16 lo = (f16)(v - (float)hi);
  size_t o = (size_t)p*1280 + co;
  cath[o] = hi; catl[o] = lo;
}

// ---------------- 3x3 conv as MFMA GEMM (f16 2-term split, 3 passes), split-K partials ----------------
__global__ __launch_bounds__(256) void conv_mfma_k(
    const f16* __restrict__ whi, const f16* __restrict__ wlo,
    const f16* __restrict__ ahi, const f16* __restrict__ alo,
    float* __restrict__ part, int Cin, int chunks, int cpt)
{
  const int K9 = 9*Cin;
  int cob = blockIdx.x * 128;
  int px0 = blockIdx.y * 128;
  int ks  = blockIdx.z;
  int kc0 = ks * chunks;
  int tid = threadIdx.x;

  __shared__ f16 sAh[128*32], sAl[128*32], sBh[128*32], sBl[128*32];

  int r = tid >> 1, h = tid & 1;
  int wb0 = ((r*64 + h*32)      ) ^ ((r&7)<<4);
  int wb1 = ((r*64 + h*32 + 16) ) ^ ((r&7)<<4);
  const f16* wArowh = whi + (size_t)(cob + r)*K9 + h*16;
  const f16* wArowl = wlo + (size_t)(cob + r)*K9 + h*16;
  int p = px0 + r;
  int py = p / 19, px = p - py*19;

  int lane = tid & 63, wid = tid >> 6;
  int lrow = lane & 15, lgrp = lane >> 4;
  int wr = wid >> 1, wc = wid & 1;
  int swz = (lrow & 7) << 4;
  int aoff[4], boff[4];
  #pragma unroll
  for (int m = 0; m < 4; ++m){
    int rA = wr*64 + m*16 + lrow;
    aoff[m] = (rA*64 + lgrp*16) ^ swz;
    int rB = wc*64 + m*16 + lrow;
    boff[m] = (rB*64 + lgrp*16) ^ swz;
  }

  f32x4 acc[4][4] = {};

  for (int kc = kc0; kc < kc0 + chunks; ++kc){
    int t = kc / cpt;                   // tap 0..8
    int ci0 = (kc - t*cpt) * 32;
    int dy = t / 3, dx = t - dy*3;
    int yy = py + dy - 1, xx = px + dx - 1;
    bool bvalid = (p < NPIX) && ((unsigned)yy < 19u) && ((unsigned)xx < 19u);

    f16x8 a0 = *(const f16x8*)(wArowh + (size_t)kc*32);
    f16x8 a1 = *(const f16x8*)(wArowh + (size_t)kc*32 + 8);
    f16x8 a2 = *(const f16x8*)(wArowl + (size_t)kc*32);
    f16x8 a3 = *(const f16x8*)(wArowl + (size_t)kc*32 + 8);
    f16x8 b0 = {}, b1 = {}, b2 = {}, b3 = {};
    if (bvalid){
      const f16* bh_src = ahi + (size_t)(yy*19+xx)*Cin + ci0 + h*16;
      const f16* bl_src = alo + (size_t)(yy*19+xx)*Cin + ci0 + h*16;
      b0 = *(const f16x8*)(bh_src);
      b1 = *(const f16x8*)(bh_src + 8);
      b2 = *(const f16x8*)(bl_src);
      b3 = *(const f16x8*)(bl_src + 8);
    }
    __syncthreads();
    *(f16x8*)((char*)sAh + wb0) = a0; *(f16x8*)((char*)sAh + wb1) = a1;
    *(f16x8*)((char*)sAl + wb0) = a2; *(f16x8*)((char*)sAl + wb1) = a3;
    *(f16x8*)((char*)sBh + wb0) = b0; *(f16x8*)((char*)sBh + wb1) = b1;
    *(f16x8*)((char*)sBl + wb0) = b2; *(f16x8*)((char*)sBl + wb1) = b3;
    __syncthreads();

    f16x8 bh[4], bl[4];
    #pragma unroll
    for (int n = 0; n < 4; ++n){
      bh[n] = *(const f16x8*)((char*)sBh + boff[n]);
      bl[n] = *(const f16x8*)((char*)sBl + boff[n]);
    }
    #pragma unroll
    for (int m = 0; m < 4; ++m){
      f16x8 ah = *(const f16x8*)((char*)sAh + aoff[m]);
      f16x8 al = *(const f16x8*)((char*)sAl + aoff[m]);
      #pragma unroll
      for (int n = 0; n < 4; ++n){
        acc[m][n] = __builtin_amdgcn_mfma_f32_16x16x32_f16(ah, bh[n], acc[m][n], 0,0,0);
        acc[m][n] = __builtin_amdgcn_mfma_f32_16x16x32_f16(ah, bl[n], acc[m][n], 0,0,0);
        acc[m][n] = __builtin_amdgcn_mfma_f32_16x16x32_f16(al, bh[n], acc[m][n], 0,0,0);
      }
    }
  }

  #pragma unroll
  for (int m = 0; m < 4; ++m){
    #pragma unroll
    for (int n = 0; n < 4; ++n){
      int pp = px0 + wc*64 + n*16 + lrow;
      if (pp < NPIX){
        int co = cob + wr*64 + m*16 + lgrp*4;
        size_t base = ((size_t)ks*1024 + co)*NPIX + pp;
        part[base          ] = acc[m][n][0];
        part[base +   NPIX ] = acc[m][n][1];
        part[base + 2*NPIX ] = acc[m][n][2];
        part[base + 3*NPIX ] = acc[m][n][3];
      }
    }
  }
}

// ---------------- reduce split-K partials (x1/64) + bias + leaky -> transposed f16 hi/lo ----------------
__global__ void reduce16v_k(const float* __restrict__ part, const float* __restrict__ bias,
                            f16* __restrict__ dhi, f16* __restrict__ dlo,
                            int Cstride, int Coff, int splitk){
  int i = blockIdx.x*256 + threadIdx.x;
  if (i >= 1024*NPIX) return;
  int co = i / NPIX, p = i - co*NPIX;
  float s = 0.f;
  for (int k = 0; k < splitk; ++k) s += part[(size_t)k*1024*NPIX + i];
  float v = leakyf(s*0.015625f + bias[co]);
  f16 hi = (f16)v;
  f16 lo = (f16)(v - (float)hi);
  size_t o = (size_t)p*Cstride + Coff + co;
  dhi[o] = hi; dlo[o] = lo;
}

// ---------------- pred 1x1 conv: act3[361][1024] (hi+lo) -> 125 ----------------
__global__ __launch_bounds__(256) void pred_conv_k(const f16* __restrict__ a3h, const f16* __restrict__ a3l,
    const float* __restrict__ wpT, const float* __restrict__ bp, float* __restrict__ pred){
  int c = threadIdx.x & 127, ph = threadIdx.x >> 7;
  int pix = blockIdx.x*2 + ph;
  __shared__ float s_in[64][2];
  float acc = 0.f;
  for (int cb = 0; cb < 1024; cb += 64){
    __syncthreads();
    if (threadIdx.x < 128){
      int k = threadIdx.x & 63, pp = threadIdx.x >> 6;
      int px2 = blockIdx.x*2 + pp;
      float v = 0.f;
      if (px2 < NPIX){
        size_t o = (size_t)px2*1024 + cb + k;
        v = (float)a3h[o] + (float)a3l[o];
      }
      s_in[k][pp] = v;
    }
    __syncthreads();
    if (c < 125){
      #pragma unroll
      for (int k = 0; k < 64; ++k)
        acc = fmaf(wpT[(cb+k)*125 + c], s_in[k][ph], acc);
    }
  }
  if (c < 125 && pix < NPIX) pred[c*NPIX + pix] = acc + bp[c];
}

// ---------------- decode boxes / scores / argmax (+ zero class counters) ----------------
__device__ const float ANCW[5] = {1.19f, 2.79f, 4.53f, 8.06f, 10.32f};
__device__ const float ANCH_[5] = {1.98f, 4.59f, 8.92f, 5.29f, 10.65f};

__global__ void decode_k(const float* __restrict__ pred, float* __restrict__ out,
                         int* __restrict__ cls_i, int* __restrict__ cnt){
  int n = blockIdx.x*256 + threadIdx.x;
  if (blockIdx.x == 0 && threadIdx.x < NCLS) cnt[threadIdx.x] = 0;
  if (n >= N_BOX) return;
  int p = n / 5, a = n % 5;
  float conf = pred[a*NPIX + p];
  float cl[20]; float m = -1e30f;
  #pragma unroll
  for (int k = 0; k < 20; ++k){ cl[k] = pred[(5 + a*20 + k)*NPIX + p]; m = fmaxf(m, cl[k]); }
  float s = 0.f;
  #pragma unroll
  for (int k = 0; k < 20; ++k){ cl[k] = expf(cl[k]-m); s += cl[k]; }
  int bi = 0; float bv = cl[0];
  #pragma unroll
  for (int k = 1; k < 20; ++k) if (cl[k] > bv){ bv = cl[k]; bi = k; }
  float score = sigmoidf_(conf) * (bv / s);
  float tx = pred[(105 + a*4 + 0)*NPIX + p];
  float ty = pred[(105 + a*4 + 1)*NPIX + p];
  float tw = pred[(105 + a*4 + 2)*NPIX + p];
  float th = pred[(105 + a*4 + 3)*NPIX + p];
  float gx = (float)(p % 19), gy = (float)(p / 19);
  float cx = (sigmoidf_(tx) + gx) * 32.f;
  float cy = (sigmoidf_(ty) + gy) * 32.f;
  float bw = expf(tw) * ANCW[a] * 32.f;
  float bh = expf(th) * ANCH_[a] * 32.f;
  float x1 = fminf(fmaxf((cx - 0.5f*bw) / 608.f, 0.f), 1.f);
  float y1 = fminf(fmaxf((cy - 0.5f*bh) / 608.f, 0.f), 1.f);
  float x2 = fminf(fmaxf((cx + 0.5f*bw) / 608.f, 0.f), 1.f);
  float y2 = fminf(fmaxf((cy + 0.5f*bh) / 608.f, 0.f), 1.f);
  out[n*4+0]=x1; out[n*4+1]=y1; out[n*4+2]=x2; out[n*4+3]=y2;
  out[7220 + n]  = score;
  out[9025 + n]  = (float)bi;
  out[10830 + n] = 0.f;          // keep init
  cls_i[n] = bi;
}

// ---------------- per-class rank, wave-parallel (1 wave per box) ----------------
__global__ __launch_bounds__(256) void rank_k(const float* __restrict__ scores,
    const int* __restrict__ cls_i, int* __restrict__ ord, int* __restrict__ cnt){
  __shared__ float s_sc[N_BOX];
  __shared__ short s_cl[N_BOX];
  int tid = threadIdx.x;
  for (int j = tid; j < N_BOX; j += 256){ s_sc[j] = scores[j]; s_cl[j] = (short)cls_i[j]; }
  __syncthreads();
  int wid = tid >> 6, lane = tid & 63;
  int i = blockIdx.x*4 + wid;
  if (i >= N_BOX) return;
  float si = s_sc[i]; short ci = s_cl[i];
  int r = 0;
  for (int j = lane; j < N_BOX; j += 64){
    float sj = s_sc[j];
    r += (int)((s_cl[j] == ci) & ((sj > si) | ((sj == si) & (j < i))));
  }
  #pragma unroll
  for (int o = 32; o; o >>= 1) r += __shfl_down(r, o);
  if (lane == 0){
    ord[ci*N_BOX + r] = i;
    atomicAdd(&cnt[ci], 1);
  }
}

// ---------------- per-class NMS: parallel bitmask build + single-wave scan ----------------
__global__ __launch_bounds__(256) void nms2_k(const float* __restrict__ boxes,
    const int* __restrict__ ord, const int* __restrict__ cnt, float* __restrict__ keep,
    unsigned long long* __restrict__ gmask){
  __shared__ float X1[N_BOX], Y1[N_BOX], X2[N_BOX], Y2[N_BOX], AR[N_BOX];
  __shared__ int IDX[N_BOX];
  __shared__ unsigned long long smask[MCAP*(MCAP/64 + 1)];   // 320*5 words
  int c = blockIdx.x, tid = threadIdx.x;
  int n = cnt[c];
  if (n <= 0) return;
  for (int t = tid; t < n; t += 256){
    int bi = ord[c*N_BOX + t];
    float x1 = boxes[bi*4+0], y1 = boxes[bi*4+1], x2 = boxes[bi*4+2], y2 = boxes[bi*4+3];
    X1[t]=x1; Y1[t]=y1; X2[t]=x2; Y2[t]=y2; AR[t]=(x2-x1)*(y2-y1);
    IDX[t]=bi;
  }
  __syncthreads();
  int nw = (n + 63) >> 6;
  bool lds = (n <= MCAP);
  unsigned long long* rows = lds ? smask : (gmask + (size_t)c*N_BOX*GNW);
  // phase A: parallel mask build (upper triangle)
  for (int task = tid; task < n*nw; task += 256){
    int i = task / nw, w = task - i*nw;
    float ax1=X1[i], ay1=Y1[i], ax2=X2[i], ay2=Y2[i], areaA=AR[i];
    unsigned long long bits = 0;
    int j0 = w << 6;
    int jb = i+1 > j0 ? i+1 : j0;
    int je = j0+64 < n ? j0+64 : n;
    for (int j = jb; j < je; ++j){
      float iw = fmaxf(1e-10f, fminf(ax2,X2[j]) - fmaxf(ax1,X1[j]));
      float ih = fmaxf(1e-10f, fminf(ay2,Y2[j]) - fmaxf(ay1,Y1[j]));
      float inter = iw*ih;
      float iou = inter / (areaA + AR[j] - inter);
      bits |= (unsigned long long)(iou > 0.5f) << (j - j0);
    }
    rows[(size_t)i*nw + w] = bits;
  }
  __syncthreads();
  // phase B: single-wave greedy scan; lane w holds suppressed-word w
  if (tid < 64){
    int lane = tid;
    unsigned long long S = 0;
    unsigned long long r0,r1,r2,r3;
    bool act = lane < nw;
    r0 = (act && 0 < n) ? rows[lane] : 0ull;
    r1 = (act && 1 < n) ? rows[(size_t)1*nw + lane] : 0ull;
    r2 = (act && 2 < n) ? rows[(size_t)2*nw + lane] : 0ull;
    r3 = (act && 3 < n) ? rows[(size_t)3*nw + lane] : 0ull;
    for (int i = 0; i < n; ++i){
      unsigned long long row = r0; r0 = r1; r1 = r2; r2 = r3;
      r3 = (act && i+4 < n) ? rows[(size_t)(i+4)*nw + lane] : 0ull;
      unsigned long long Siw = __shfl(S, i >> 6);
      if (!((Siw >> (i & 63)) & 1ull)){
        if (lane == 0) keep[IDX[i]] = 1.f;
        S |= row;
      }
    }
  }
}

static inline size_t align256(size_t x){ return (x + 255) & ~(size_t)255; }

extern "C" void kernel_launch(void* const* d_in, const int* in_sizes, int n_in,
                              void* d_out, int out_size, void* d_ws, size_t ws_size,
                              hipStream_t stream){
  const float* feat2 = (const float*)d_in[0];   // (512,38,38)
  const float* feat3 = (const float*)d_in[1];   // (1024,19,19)
  const float* w1a = (const float*)d_in[2];
  const float* b1a = (const float*)d_in[3];
  const float* w1b = (const float*)d_in[4];
  const float* b1b = (const float*)d_in[5];
  const float* wr  = (const float*)d_in[6];
  const float* br  = (const float*)d_in[7];
  const float* w2  = (const float*)d_in[8];
  const float* b2  = (const float*)d_in[9];
  const float* wp  = (const float*)d_in[10];
  const float* bp  = (const float*)d_in[11];
  float* out = (float*)d_out;
  char* ws = (char*)d_ws;

  size_t off = 0;
  float* part = (float*)(ws + off); off = align256(off + (size_t)16*1024*NPIX*4);
  f16* wh   = (f16*)(ws + off); off = align256(off + (size_t)1024*1280*9*2);
  f16* wl   = (f16*)(ws + off); off = align256(off + (size_t)1024*1280*9*2);
  f16* a1h  = (f16*)(ws + off); off = align256(off + (size_t)NPIX*1024*2);
  f16* a1l  = (f16*)(ws + off); off = align256(off + (size_t)NPIX*1024*2);
  f16* a2h  = (f16*)(ws + off); off = align256(off + (size_t)NPIX*1024*2);
  f16* a2l  = (f16*)(ws + off); off = align256(off + (size_t)NPIX*1024*2);
  f16* a3h  = (f16*)(ws + off); off = align256(off + (size_t)NPIX*1024*2);
  f16* a3l  = (f16*)(ws + off); off = align256(off + (size_t)NPIX*1024*2);
  f16* cath = (f16*)(ws + off); off = align256(off + (size_t)NPIX*1280*2);
  f16* catl = (f16*)(ws + off); off = align256(off + (size_t)NPIX*1280*2);
  float* pred = (float*)(ws + off); off = align256(off + (size_t)125*NPIX*4);
  float* wrT  = (float*)(ws + off); off = align256(off + (size_t)512*64*4);
  float* wpT  = (float*)(ws + off); off = align256(off + (size_t)1024*125*4);
  int* cls_i  = (int*)(ws + off); off = align256(off + (size_t)N_BOX*4);
  int* ord    = (int*)(ws + off); off = align256(off + (size_t)NCLS*N_BOX*4);
  int* cnt    = (int*)(ws + off); off = align256(off + (size_t)NCLS*4);
  unsigned long long* gmask = (unsigned long long*)part;   // part is free by NMS time

  transpose_k<<<(64*512 + 255)/256, 256, 0, stream>>>(wr, wrT, 64, 512);
  transpose_k<<<(125*1024 + 255)/256, 256, 0, stream>>>(wp, wpT, 125, 1024);
  act1prep_k<<<(NPIX*1024 + 255)/256, 256, 0, stream>>>(feat3, a1h, a1l);
  reorg_conv_k<<<361, 256, 0, stream>>>(feat2, wrT, br, cath, catl);

  // conv1: act1 (Cin=1024) -> act2
  wprep_k<<<(1024*1024 + 255)/256, 256, 0, stream>>>(w1a, wh, wl, 1024, 1024*1024);
  { dim3 g(8, 3, 16);
    conv_mfma_k<<<g, 256, 0, stream>>>(wh, wl, a1h, a1l, part, 1024, 18, 32); }
  reduce16v_k<<<(1024*NPIX + 255)/256, 256, 0, stream>>>(part, b1a, a2h, a2l, 1024, 0, 16);

  // conv2: act2 (Cin=1024) -> cat[256:1280)
  wprep_k<<<(1024*1024 + 255)/256, 256, 0, stream>>>(w1b, wh, wl, 1024, 1024*1024);
  { dim3 g(8, 3, 16);
    conv_mfma_k<<<g, 256, 0, stream>>>(wh, wl, a2h, a2l, part, 1024, 18, 32); }
  reduce16v_k<<<(1024*NPIX + 255)/256, 256, 0, stream>>>(part, b1b, cath, catl, 1280, 256, 16);

  // conv3: cat (Cin=1280) -> act3
  wprep_k<<<(1024*1280 + 255)/256, 256, 0, stream>>>(w2, wh, wl, 1280, 1024*1280);
  { dim3 g(8, 3, 15);
    conv_mfma_k<<<g, 256, 0, stream>>>(wh, wl, cath, catl, part, 1280, 24, 40); }
  reduce16v_k<<<(1024*NPIX + 255)/256, 256, 0, stream>>>(part, b2, a3h, a3l, 1024, 0, 15);

  // pred 1x1 + decode + NMS
  pred_conv_k<<<181, 256, 0, stream>>>(a3h, a3l, wpT, bp, pred);
  decode_k<<<8, 256, 0, stream>>>(pred, out, cls_i, cnt);
  rank_k<<<(N_BOX + 3)/4, 256, 0, stream>>>(out + 7220, cls_i, ord, cnt);
  nms2_k<<<NCLS, 256, 0, stream>>>(out, ord, cnt, out + 10830, gmask);
}

// Round 7
// 318.197 us; speedup vs baseline: 1.0703x; 1.0703x over previous
//
#include <hip/hip_runtime.h>

typedef _Float16 f16;
typedef _Float16 f16x8 __attribute__((ext_vector_type(8)));
typedef float f32x4 __attribute__((ext_vector_type(4)));

#define N_BOX 1805
#define NPIX 361
#define NCLS 20
#define GNW 29            // ceil(1805/64) mask words per row
#define MB_ROWS 226       // ceil(1805/8) rows per maskbuild block

__device__ __forceinline__ float leakyf(float x){ return x > 0.f ? x : 0.1f*x; }
__device__ __forceinline__ float sigmoidf_(float x){ return 1.f/(1.f + expf(-x)); }

// ---------------- small transpose: dst[C][R] = src[R][C] (fp32, for wrT/wpT) ----------------
__global__ void transpose_k(const float* __restrict__ src, float* __restrict__ dst, int R, int C){
  int i = blockIdx.x*256 + threadIdx.x;
  if (i < R*C){ int r = i / C, c = i % C; dst[c*R + r] = src[i]; }
}

// ---------------- weight prep: w[Cout][Cin][9] fp32 -> whi/wlo[Cout][9][Cin] f16, scaled x64 ----------------
__global__ void wprep_k(const float* __restrict__ w, f16* __restrict__ whi, f16* __restrict__ wlo,
                        int Cin, int total){
  int i = blockIdx.x*256 + threadIdx.x;   // over Cout*Cin
  if (i >= total) return;
  int co = i / Cin, ci = i - co*Cin;
  const float* src = w + (size_t)i*9;     // [co][ci][0..9)
  int K9 = 9*Cin;
  size_t dbase = (size_t)co*K9 + ci;
  #pragma unroll
  for (int t = 0; t < 9; ++t){
    float v = src[t]*64.f;
    f16 hi = (f16)v;
    f16 lo = (f16)(v - (float)hi);
    whi[dbase + (size_t)t*Cin] = hi;
    wlo[dbase + (size_t)t*Cin] = lo;
  }
}

// ---------------- act1 prep: feat3[1024][361] fp32 -> a1hi/a1lo[361][1024] f16 ----------------
__global__ void act1prep_k(const float* __restrict__ feat3, f16* __restrict__ ah, f16* __restrict__ al){
  int i = blockIdx.x*256 + threadIdx.x;  // over 361*1024
  if (i >= NPIX*1024) return;
  int p = i >> 10, c = i & 1023;
  float v = feat3[c*NPIX + p];
  f16 hi = (f16)v; f16 lo = (f16)(v - (float)hi);
  ah[i] = hi; al[i] = lo;
}

// ---------------- reorg path: leaky(conv1x1(feat2, wr)+br) -> reorg -> cat[ ][0:256) f16 hi/lo ----------------
__global__ __launch_bounds__(256) void reorg_conv_k(const float* __restrict__ feat2,
    const float* __restrict__ wrT, const float* __restrict__ br,
    f16* __restrict__ cath, f16* __restrict__ catl){
  int c  = threadIdx.x & 63;
  int pq = threadIdx.x >> 6;
  int pix = blockIdx.x*4 + pq;      // 0..1443
  int y = pix / 38, x = pix % 38;
  __shared__ float s_in[64][4];
  float acc = br[c];
  for (int cb = 0; cb < 512; cb += 64){
    __syncthreads();
    { int k = threadIdx.x >> 2, pp = threadIdx.x & 3;
      s_in[k][pp] = feat2[(cb + k)*1444 + blockIdx.x*4 + pp]; }
    __syncthreads();
    #pragma unroll
    for (int k = 0; k < 64; ++k)
      acc = fmaf(wrT[(cb+k)*64 + c], s_in[k][pq], acc);
  }
  float v = leakyf(acc);
  int co = ((y & 1)*2 + (x & 1))*64 + c;   // reorg channel mapping
  int p = (y>>1)*19 + (x>>1);
  f16 hi = (f16)v; f16 lo = (f16)(v - (float)hi);
  size_t o = (size_t)p*1280 + co;
  cath[o] = hi; catl[o] = lo;
}

// ---------------- 3x3 conv as MFMA GEMM (f16 2-term split, 3 passes), split-K partials ----------------
__global__ __launch_bounds__(256) void conv_mfma_k(
    const f16* __restrict__ whi, const f16* __restrict__ wlo,
    const f16* __restrict__ ahi, const f16* __restrict__ alo,
    float* __restrict__ part, int Cin, int chunks, int cpt)
{
  const int K9 = 9*Cin;
  int cob = blockIdx.x * 128;
  int px0 = blockIdx.y * 128;
  int ks  = blockIdx.z;
  int kc0 = ks * chunks;
  int tid = threadIdx.x;

  __shared__ f16 sAh[128*32], sAl[128*32], sBh[128*32], sBl[128*32];

  int r = tid >> 1, h = tid & 1;
  int wb0 = ((r*64 + h*32)      ) ^ ((r&7)<<4);
  int wb1 = ((r*64 + h*32 + 16) ) ^ ((r&7)<<4);
  const f16* wArowh = whi + (size_t)(cob + r)*K9 + h*16;
  const f16* wArowl = wlo + (size_t)(cob + r)*K9 + h*16;
  int p = px0 + r;
  int py = p / 19, px = p - py*19;

  int lane = tid & 63, wid = tid >> 6;
  int lrow = lane & 15, lgrp = lane >> 4;
  int wr = wid >> 1, wc = wid & 1;
  int swz = (lrow & 7) << 4;
  int aoff[4], boff[4];
  #pragma unroll
  for (int m = 0; m < 4; ++m){
    int rA = wr*64 + m*16 + lrow;
    aoff[m] = (rA*64 + lgrp*16) ^ swz;
    int rB = wc*64 + m*16 + lrow;
    boff[m] = (rB*64 + lgrp*16) ^ swz;
  }

  f32x4 acc[4][4] = {};

  for (int kc = kc0; kc < kc0 + chunks; ++kc){
    int t = kc / cpt;                   // tap 0..8
    int ci0 = (kc - t*cpt) * 32;
    int dy = t / 3, dx = t - dy*3;
    int yy = py + dy - 1, xx = px + dx - 1;
    bool bvalid = (p < NPIX) && ((unsigned)yy < 19u) && ((unsigned)xx < 19u);

    f16x8 a0 = *(const f16x8*)(wArowh + (size_t)kc*32);
    f16x8 a1 = *(const f16x8*)(wArowh + (size_t)kc*32 + 8);
    f16x8 a2 = *(const f16x8*)(wArowl + (size_t)kc*32);
    f16x8 a3 = *(const f16x8*)(wArowl + (size_t)kc*32 + 8);
    f16x8 b0 = {}, b1 = {}, b2 = {}, b3 = {};
    if (bvalid){
      const f16* bh_src = ahi + (size_t)(yy*19+xx)*Cin + ci0 + h*16;
      const f16* bl_src = alo + (size_t)(yy*19+xx)*Cin + ci0 + h*16;
      b0 = *(const f16x8*)(bh_src);
      b1 = *(const f16x8*)(bh_src + 8);
      b2 = *(const f16x8*)(bl_src);
      b3 = *(const f16x8*)(bl_src + 8);
    }
    __syncthreads();
    *(f16x8*)((char*)sAh + wb0) = a0; *(f16x8*)((char*)sAh + wb1) = a1;
    *(f16x8*)((char*)sAl + wb0) = a2; *(f16x8*)((char*)sAl + wb1) = a3;
    *(f16x8*)((char*)sBh + wb0) = b0; *(f16x8*)((char*)sBh + wb1) = b1;
    *(f16x8*)((char*)sBl + wb0) = b2; *(f16x8*)((char*)sBl + wb1) = b3;
    __syncthreads();

    f16x8 bh[4], bl[4];
    #pragma unroll
    for (int n = 0; n < 4; ++n){
      bh[n] = *(const f16x8*)((char*)sBh + boff[n]);
      bl[n] = *(const f16x8*)((char*)sBl + boff[n]);
    }
    #pragma unroll
    for (int m = 0; m < 4; ++m){
      f16x8 ah = *(const f16x8*)((char*)sAh + aoff[m]);
      f16x8 al = *(const f16x8*)((char*)sAl + aoff[m]);
      #pragma unroll
      for (int n = 0; n < 4; ++n){
        acc[m][n] = __builtin_amdgcn_mfma_f32_16x16x32_f16(ah, bh[n], acc[m][n], 0,0,0);
        acc[m][n] = __builtin_amdgcn_mfma_f32_16x16x32_f16(ah, bl[n], acc[m][n], 0,0,0);
        acc[m][n] = __builtin_amdgcn_mfma_f32_16x16x32_f16(al, bh[n], acc[m][n], 0,0,0);
      }
    }
  }

  #pragma unroll
  for (int m = 0; m < 4; ++m){
    #pragma unroll
    for (int n = 0; n < 4; ++n){
      int pp = px0 + wc*64 + n*16 + lrow;
      if (pp < NPIX){
        int co = cob + wr*64 + m*16 + lgrp*4;
        size_t base = ((size_t)ks*1024 + co)*NPIX + pp;
        part[base          ] = acc[m][n][0];
        part[base +   NPIX ] = acc[m][n][1];
        part[base + 2*NPIX ] = acc[m][n][2];
        part[base + 3*NPIX ] = acc[m][n][3];
      }
    }
  }
}

// ---------------- reduce split-K partials (x1/64) + bias + leaky -> transposed f16 hi/lo ----------------
__global__ void reduce16v_k(const float* __restrict__ part, const float* __restrict__ bias,
                            f16* __restrict__ dhi, f16* __restrict__ dlo,
                            int Cstride, int Coff, int splitk){
  int i = blockIdx.x*256 + threadIdx.x;
  if (i >= 1024*NPIX) return;
  int co = i / NPIX, p = i - co*NPIX;
  float s = 0.f;
  for (int k = 0; k < splitk; ++k) s += part[(size_t)k*1024*NPIX + i];
  float v = leakyf(s*0.015625f + bias[co]);
  f16 hi = (f16)v;
  f16 lo = (f16)(v - (float)hi);
  size_t o = (size_t)p*Cstride + Coff + co;
  dhi[o] = hi; dlo[o] = lo;
}

// ---------------- pred 1x1 conv: act3[361][1024] (hi+lo) -> 125 ----------------
__global__ __launch_bounds__(256) void pred_conv_k(const f16* __restrict__ a3h, const f16* __restrict__ a3l,
    const float* __restrict__ wpT, const float* __restrict__ bp, float* __restrict__ pred){
  int c = threadIdx.x & 127, ph = threadIdx.x >> 7;
  int pix = blockIdx.x*2 + ph;
  __shared__ float s_in[64][2];
  float acc = 0.f;
  for (int cb = 0; cb < 1024; cb += 64){
    __syncthreads();
    if (threadIdx.x < 128){
      int k = threadIdx.x & 63, pp = threadIdx.x >> 6;
      int px2 = blockIdx.x*2 + pp;
      float v = 0.f;
      if (px2 < NPIX){
        size_t o = (size_t)px2*1024 + cb + k;
        v = (float)a3h[o] + (float)a3l[o];
      }
      s_in[k][pp] = v;
    }
    __syncthreads();
    if (c < 125){
      #pragma unroll
      for (int k = 0; k < 64; ++k)
        acc = fmaf(wpT[(cb+k)*125 + c], s_in[k][ph], acc);
    }
  }
  if (c < 125 && pix < NPIX) pred[c*NPIX + pix] = acc + bp[c];
}

// ---------------- decode boxes / scores / argmax (+ zero class counters) ----------------
__device__ const float ANCW[5] = {1.19f, 2.79f, 4.53f, 8.06f, 10.32f};
__device__ const float ANCH_[5] = {1.98f, 4.59f, 8.92f, 5.29f, 10.65f};

__global__ void decode_k(const float* __restrict__ pred, float* __restrict__ out,
                         int* __restrict__ cls_i, int* __restrict__ cnt){
  int n = blockIdx.x*256 + threadIdx.x;
  if (blockIdx.x == 0 && threadIdx.x < NCLS) cnt[threadIdx.x] = 0;
  if (n >= N_BOX) return;
  int p = n / 5, a = n % 5;
  float conf = pred[a*NPIX + p];
  float cl[20]; float m = -1e30f;
  #pragma unroll
  for (int k = 0; k < 20; ++k){ cl[k] = pred[(5 + a*20 + k)*NPIX + p]; m = fmaxf(m, cl[k]); }
  float s = 0.f;
  #pragma unroll
  for (int k = 0; k < 20; ++k){ cl[k] = expf(cl[k]-m); s += cl[k]; }
  int bi = 0; float bv = cl[0];
  #pragma unroll
  for (int k = 1; k < 20; ++k) if (cl[k] > bv){ bv = cl[k]; bi = k; }
  float score = sigmoidf_(conf) * (bv / s);
  float tx = pred[(105 + a*4 + 0)*NPIX + p];
  float ty = pred[(105 + a*4 + 1)*NPIX + p];
  float tw = pred[(105 + a*4 + 2)*NPIX + p];
  float th = pred[(105 + a*4 + 3)*NPIX + p];
  float gx = (float)(p % 19), gy = (float)(p / 19);
  float cx = (sigmoidf_(tx) + gx) * 32.f;
  float cy = (sigmoidf_(ty) + gy) * 32.f;
  float bw = expf(tw) * ANCW[a] * 32.f;
  float bh = expf(th) * ANCH_[a] * 32.f;
  float x1 = fminf(fmaxf((cx - 0.5f*bw) / 608.f, 0.f), 1.f);
  float y1 = fminf(fmaxf((cy - 0.5f*bh) / 608.f, 0.f), 1.f);
  float x2 = fminf(fmaxf((cx + 0.5f*bw) / 608.f, 0.f), 1.f);
  float y2 = fminf(fmaxf((cy + 0.5f*bh) / 608.f, 0.f), 1.f);
  out[n*4+0]=x1; out[n*4+1]=y1; out[n*4+2]=x2; out[n*4+3]=y2;
  out[7220 + n]  = score;
  out[9025 + n]  = (float)bi;
  out[10830 + n] = 0.f;          // keep init
  cls_i[n] = bi;
}

// ---------------- per-class rank, wave-parallel (1 wave per box) ----------------
__global__ __launch_bounds__(256) void rank_k(const float* __restrict__ scores,
    const int* __restrict__ cls_i, int* __restrict__ ord, int* __restrict__ cnt){
  __shared__ float s_sc[N_BOX];
  __shared__ short s_cl[N_BOX];
  int tid = threadIdx.x;
  for (int j = tid; j < N_BOX; j += 256){ s_sc[j] = scores[j]; s_cl[j] = (short)cls_i[j]; }
  __syncthreads();
  int wid = tid >> 6, lane = tid & 63;
  int i = blockIdx.x*4 + wid;
  if (i >= N_BOX) return;
  float si = s_sc[i]; short ci = s_cl[i];
  int r = 0;
  for (int j = lane; j < N_BOX; j += 64){
    float sj = s_sc[j];
    r += (int)((s_cl[j] == ci) & ((sj > si) | ((sj == si) & (j < i))));
  }
  #pragma unroll
  for (int o = 32; o; o >>= 1) r += __shfl_down(r, o);
  if (lane == 0){
    ord[ci*N_BOX + r] = i;
    atomicAdd(&cnt[ci], 1);
  }
}

// ---------------- NMS phase A: parallel suppression-mask build ----------------
// grid (NCLS, 8): block handles rows [chunk*MB_ROWS, ...) of class c.
// task mapping: lanes share j-range (broadcast LDS reads), consecutive i.
__global__ __launch_bounds__(256) void maskbuild_k(const float* __restrict__ boxes,
    const int* __restrict__ ord, const int* __restrict__ cnt,
    unsigned long long* __restrict__ gmask){
  __shared__ float X1[N_BOX], Y1[N_BOX], X2[N_BOX], Y2[N_BOX], AR[N_BOX];
  int c = blockIdx.x, chunk = blockIdx.y, tid = threadIdx.x;
  int n = cnt[c];
  int r0 = chunk*MB_ROWS;
  if (n <= 0 || r0 >= n) return;
  int r1 = r0 + MB_ROWS; if (r1 > n) r1 = n;
  int rows_here = r1 - r0;
  for (int t = tid; t < n; t += 256){
    int bi = ord[c*N_BOX + t];
    float x1 = boxes[bi*4+0], y1 = boxes[bi*4+1], x2 = boxes[bi*4+2], y2 = boxes[bi*4+3];
    X1[t]=x1; Y1[t]=y1; X2[t]=x2; Y2[t]=y2; AR[t]=(x2-x1)*(y2-y1);
  }
  __syncthreads();
  int nw = (n + 63) >> 6;
  unsigned long long* rows = gmask + (size_t)c*N_BOX*GNW;
  for (int task = tid; task < rows_here*nw; task += 256){
    int w = task / rows_here, ri = task - w*rows_here;
    int i = r0 + ri;
    float ax1=X1[i], ay1=Y1[i], ax2=X2[i], ay2=Y2[i], areaA=AR[i];
    unsigned long long bits = 0;
    int j0 = w << 6;
    int jb = i+1 > j0 ? i+1 : j0;
    int je = j0+64 < n ? j0+64 : n;
    for (int j = jb; j < je; ++j){
      float iw = fmaxf(1e-10f, fminf(ax2,X2[j]) - fmaxf(ax1,X1[j]));
      float ih = fmaxf(1e-10f, fminf(ay2,Y2[j]) - fmaxf(ay1,Y1[j]));
      float inter = iw*ih;
      float iou = inter / (areaA + AR[j] - inter);
      bits |= (unsigned long long)(iou > 0.5f) << (j - j0);
    }
    rows[(size_t)i*GNW + w] = bits;
  }
}

// ---------------- NMS phase B: word-centric greedy scan, 1 wave per class ----------------
__global__ __launch_bounds__(64) void nmsscan_k(const int* __restrict__ ord,
    const int* __restrict__ cnt, const unsigned long long* __restrict__ gmask,
    float* __restrict__ keep){
  __shared__ int sidx[N_BOX];
  int c = blockIdx.x, lane = threadIdx.x;
  int n = cnt[c];
  if (n <= 0) return;
  int nw = (n + 63) >> 6;
  for (int t = lane; t < n; t += 64) sidx[t] = ord[c*N_BOX + t];
  __syncthreads();
  const unsigned long long* rows = gmask + (size_t)c*N_BOX*GNW;
  bool act = lane < nw;
  unsigned long long S = 0;                     // suppressed bits, word `lane`
  unsigned long long diag = (lane < n) ? rows[(size_t)lane*GNW + 0] : 0ull;  // diag block, word 0
  for (int w = 0; w < nw; ++w){
    int base = w << 6;
    int nb = n - base; if (nb > 64) nb = 64;
    // broadcast suppressed word w
    unsigned int slo = (unsigned)__builtin_amdgcn_readlane((int)(unsigned)S, w);
    unsigned int shi = (unsigned)__builtin_amdgcn_readlane((int)(unsigned)(S >> 32), w);
    unsigned long long sup = ((unsigned long long)shi << 32) | slo;
    unsigned long long validm = (nb >= 64) ? ~0ull : ((1ull << nb) - 1ull);
    unsigned long long avail = ~sup & validm;
    unsigned long long kmask = 0;
    // prefetch next diag block word
    unsigned long long diag_next = 0;
    if (w+1 < nw){
      int i2 = base + 64 + lane;
      if (i2 < n) diag_next = rows[(size_t)i2*GNW + (w+1)];
    }
    while (avail){
      int b = __builtin_ctzll(avail);
      kmask |= 1ull << b;
      unsigned int dlo = (unsigned)__builtin_amdgcn_readlane((int)(unsigned)diag, b);
      unsigned int dhi = (unsigned)__builtin_amdgcn_readlane((int)(unsigned)(diag >> 32), b);
      unsigned long long drow = ((unsigned long long)dhi << 32) | dlo;
      sup |= drow;
      avail &= ~(1ull << b);
      avail &= ~sup;
      if (act && lane > w)
        S |= rows[(size_t)(base + b)*GNW + lane];   // cross-word suppression (off critical chain)
    }
    if ((kmask >> lane) & 1ull) keep[sidx[base + lane]] = 1.f;
    diag = diag_next;
  }
}

static inline size_t align256(size_t x){ return (x + 255) & ~(size_t)255; }

extern "C" void kernel_launch(void* const* d_in, const int* in_sizes, int n_in,
                              void* d_out, int out_size, void* d_ws, size_t ws_size,
                              hipStream_t stream){
  const float* feat2 = (const float*)d_in[0];   // (512,38,38)
  const float* feat3 = (const float*)d_in[1];   // (1024,19,19)
  const float* w1a = (const float*)d_in[2];
  const float* b1a = (const float*)d_in[3];
  const float* w1b = (const float*)d_in[4];
  const float* b1b = (const float*)d_in[5];
  const float* wr  = (const float*)d_in[6];
  const float* br  = (const float*)d_in[7];
  const float* w2  = (const float*)d_in[8];
  const float* b2  = (const float*)d_in[9];
  const float* wp  = (const float*)d_in[10];
  const float* bp  = (const float*)d_in[11];
  float* out = (float*)d_out;
  char* ws = (char*)d_ws;

  size_t off = 0;
  float* part = (float*)(ws + off); off = align256(off + (size_t)16*1024*NPIX*4);
  f16* wh   = (f16*)(ws + off); off = align256(off + (size_t)1024*1280*9*2);
  f16* wl   = (f16*)(ws + off); off = align256(off + (size_t)1024*1280*9*2);
  f16* a1h  = (f16*)(ws + off); off = align256(off + (size_t)NPIX*1024*2);
  f16* a1l  = (f16*)(ws + off); off = align256(off + (size_t)NPIX*1024*2);
  f16* a2h  = (f16*)(ws + off); off = align256(off + (size_t)NPIX*1024*2);
  f16* a2l  = (f16*)(ws + off); off = align256(off + (size_t)NPIX*1024*2);
  f16* a3h  = (f16*)(ws + off); off = align256(off + (size_t)NPIX*1024*2);
  f16* a3l  = (f16*)(ws + off); off = align256(off + (size_t)NPIX*1024*2);
  f16* cath = (f16*)(ws + off); off = align256(off + (size_t)NPIX*1280*2);
  f16* catl = (f16*)(ws + off); off = align256(off + (size_t)NPIX*1280*2);
  float* pred = (float*)(ws + off); off = align256(off + (size_t)125*NPIX*4);
  float* wrT  = (float*)(ws + off); off = align256(off + (size_t)512*64*4);
  float* wpT  = (float*)(ws + off); off = align256(off + (size_t)1024*125*4);
  int* cls_i  = (int*)(ws + off); off = align256(off + (size_t)N_BOX*4);
  int* ord    = (int*)(ws + off); off = align256(off + (size_t)NCLS*N_BOX*4);
  int* cnt    = (int*)(ws + off); off = align256(off + (size_t)NCLS*4);
  unsigned long long* gmask = (unsigned long long*)part;   // part free by NMS time (8.4MB < 23.6MB)

  transpose_k<<<(64*512 + 255)/256, 256, 0, stream>>>(wr, wrT, 64, 512);
  transpose_k<<<(125*1024 + 255)/256, 256, 0, stream>>>(wp, wpT, 125, 1024);
  act1prep_k<<<(NPIX*1024 + 255)/256, 256, 0, stream>>>(feat3, a1h, a1l);
  reorg_conv_k<<<361, 256, 0, stream>>>(feat2, wrT, br, cath, catl);

  // conv1: act1 (Cin=1024) -> act2
  wprep_k<<<(1024*1024 + 255)/256, 256, 0, stream>>>(w1a, wh, wl, 1024, 1024*1024);
  { dim3 g(8, 3, 16);
    conv_mfma_k<<<g, 256, 0, stream>>>(wh, wl, a1h, a1l, part, 1024, 18, 32); }
  reduce16v_k<<<(1024*NPIX + 255)/256, 256, 0, stream>>>(part, b1a, a2h, a2l, 1024, 0, 16);

  // conv2: act2 (Cin=1024) -> cat[256:1280)
  wprep_k<<<(1024*1024 + 255)/256, 256, 0, stream>>>(w1b, wh, wl, 1024, 1024*1024);
  { dim3 g(8, 3, 16);
    conv_mfma_k<<<g, 256, 0, stream>>>(wh, wl, a2h, a2l, part, 1024, 18, 32); }
  reduce16v_k<<<(1024*NPIX + 255)/256, 256, 0, stream>>>(part, b1b, cath, catl, 1280, 256, 16);

  // conv3: cat (Cin=1280) -> act3
  wprep_k<<<(1024*1280 + 255)/256, 256, 0, stream>>>(w2, wh, wl, 1280, 1024*1280);
  { dim3 g(8, 3, 15);
    conv_mfma_k<<<g, 256, 0, stream>>>(wh, wl, cath, catl, part, 1280, 24, 40); }
  reduce16v_k<<<(1024*NPIX + 255)/256, 256, 0, stream>>>(part, b2, a3h, a3l, 1024, 0, 15);

  // pred 1x1 + decode + NMS
  pred_conv_k<<<181, 256, 0, stream>>>(a3h, a3l, wpT, bp, pred);
  decode_k<<<8, 256, 0, stream>>>(pred, out, cls_i, cnt);
  rank_k<<<(N_BOX + 3)/4, 256, 0, stream>>>(out + 7220, cls_i, ord, cnt);
  { dim3 mg(NCLS, 8);
    maskbuild_k<<<mg, 256, 0, stream>>>(out, ord, cnt, gmask); }
  nmsscan_k<<<NCLS, 64, 0, stream>>>(ord, cnt, gmask, out + 10830);
}